// Round 1
// baseline (226.903 us; speedup 1.0000x reference)
//
#include <hip/hip_runtime.h>
#include <hip/hip_bf16.h>
#include <stdint.h>

// Problem constants
#define LNUM   2
#define F0     64
#define F1     32
#define NBASIS 8
#define WH     64     // radial MLP hidden width
#define RWN    192    // 2*F0 + 2*F1
#define NINVD  64
#define NVECD  16
#define BB     4
#define NN     512

// Tuning constants
#define TROWS  4096
#define TSCALE 256.0f      // TROWS / DMAX, DMAX=16
#define NF     388         // per-node row: hm(64)|hsv(32)|hvv(96)|hv0(192)|x(3)|pad(1)
#define SSPLIT 16          // sender splits
#define CHUNK  32          // NN / SSPLIT senders per block
#define ACC    160         // 64 (a0) + 96 (a1) accumulated features
#define RTILES 8           // receiver tiles of 64 per batch
#define INV_OFF (BB * NN * NVECD * 3)   // 98304: vecf comes first in d_out

// ---------------------------------------------------------------------------
// Radial table: rw(d) = silu(rb(d) @ Wr1) @ Wr2, stored bf16, columns permuted
// into 4 slices of 48 = [w0(16)|w3(16)|w1(8)|w2(8)] so each wave reads 96B.
// Row TROWS is all zeros (used for the masked diagonal s==r).
// ---------------------------------------------------------------------------
__global__ void table_k(const float* __restrict__ Wr1, const float* __restrict__ Wr2,
                        __hip_bfloat16* __restrict__ table) {
  int row  = blockIdx.x;                 // 0 .. LNUM*(TROWS+1)-1
  int l    = row / (TROWS + 1);
  int j    = row - l * (TROWS + 1);
  int lane = threadIdx.x;                // 64 threads
  __shared__ float t[WH];
  if (j == TROWS) {
    for (int c = 0; c < 3; c++)
      table[(size_t)row * RWN + c * 64 + lane] = __float2bfloat16(0.0f);
    return;
  }
  float d = (float)j * (1.0f / TSCALE);
  float rb[NBASIS];
#pragma unroll
  for (int b = 0; b < NBASIS; b++) {
    float dd = d - (4.0f / 7.0f) * (float)b;   // centers = linspace(0,4,8)
    rb[b] = __expf(-4.0f * dd * dd);
  }
  float acc = 0.0f;
#pragma unroll
  for (int b = 0; b < NBASIS; b++) acc += rb[b] * Wr1[(l * NBASIS + b) * WH + lane];
  t[lane] = acc / (1.0f + __expf(-acc));       // silu
  __syncthreads();
#pragma unroll
  for (int c = 0; c < 3; c++) {
    int p = c * 64 + lane;                     // permuted column
    int w = p / 48, o = p - w * 48;
    int col;
    if      (o < 16) col = 16 * w + o;             // w0 slice
    else if (o < 32) col = 64 + 16 * w + (o - 16); // w3 slice
    else if (o < 40) col = 128 + 8 * w + (o - 32); // w1 slice
    else             col = 160 + 8 * w + (o - 40); // w2 slice
    float a = 0.0f;
    for (int k = 0; k < WH; k++) a += t[k] * Wr2[(l * WH + k) * RWN + col];
    table[(size_t)row * RWN + p] = __float2bfloat16(a);
  }
}

// h_s = broadcast embed row; h_v = 0
__global__ void init_k(const float* __restrict__ embed,
                       float* __restrict__ h_s, float* __restrict__ h_v) {
  int i = blockIdx.x * 256 + threadIdx.x;
  if (i < BB * NN * F0) h_s[i] = embed[i % F0];
  if (i < BB * NN * F1 * 3) h_v[i] = 0.0f;
}

// ---------------------------------------------------------------------------
// Per-node precompute for layer l (weights pre-offset by caller):
// nf[node] = [ hm = h_s@Wm (64) | hsv = h_s@Wsv (32) | hvv[c][i] = (h_v^T Wvv) (96)
//            | hv0[i][f] = h_v[:,i]@Wv0 (192) | x (3) | pad ]
// ---------------------------------------------------------------------------
__global__ void nodeprep_k(const float* __restrict__ h_s, const float* __restrict__ h_v,
                           const float* __restrict__ x,
                           const float* __restrict__ Wm, const float* __restrict__ Wsv,
                           const float* __restrict__ Wvv, const float* __restrict__ Wv0,
                           float* __restrict__ nf) {
  int node = blockIdx.x;      // 0 .. BB*NN-1
  int lane = threadIdx.x;     // 64
  __shared__ float hs[F0];
  __shared__ float hv[F1 * 3];
  hs[lane] = h_s[(size_t)node * F0 + lane];
  hv[lane] = h_v[(size_t)node * F1 * 3 + lane];
  if (lane < 32) hv[64 + lane] = h_v[(size_t)node * F1 * 3 + 64 + lane];
  __syncthreads();
  float* out = nf + (size_t)node * NF;
  {  // hm
    float a = 0.0f;
    for (int k = 0; k < F0; k++) a += hs[k] * Wm[k * F0 + lane];
    out[lane] = a;
  }
  if (lane < F1) {  // hsv
    float a = 0.0f;
    for (int k = 0; k < F0; k++) a += hs[k] * Wsv[k * F1 + lane];
    out[64 + lane] = a;
  }
  for (int o = lane; o < 96; o += 64) {  // hvv[c][i] = sum_f h_v[f][i] * Wvv[f][c]
    int c = o / 3, i = o - c * 3;
    float a = 0.0f;
    for (int f = 0; f < F1; f++) a += hv[f * 3 + i] * Wvv[f * F1 + c];
    out[96 + o] = a;
  }
  for (int o = lane; o < 192; o += 64) {  // hv0[i][f] = sum_c h_v[c][i] * Wv0[c][f]
    int i = o >> 6, f = o & 63;
    float a = 0.0f;
    for (int c = 0; c < F1; c++) a += hv[c * 3 + i] * Wv0[c * F0 + f];
    out[192 + o] = a;
  }
  if (lane < 3) out[384 + lane] = x[(size_t)node * 3 + lane];
  if (lane == 3) out[387] = 0.0f;
}

// ---------------------------------------------------------------------------
// Message + scatter kernel. Block = (batch, 64-receiver tile, 32-sender chunk).
// 4 waves = 4 feature slices; lane = receiver. Sender data broadcast from LDS;
// radial weights gathered per-lane from bf16 table (software-pipelined).
// Writes deterministic partial sums: partial[b][ss][feat(160)][n].
// ---------------------------------------------------------------------------
__launch_bounds__(256, 2)
__global__ void msg_k(const float* __restrict__ nf, const __hip_bfloat16* __restrict__ table_l,
                      const float* __restrict__ x, float* __restrict__ partial) {
  __shared__ float snf[CHUNK][NF];   // 48.5 KB
  int bid = blockIdx.x;
  int b   = bid / (RTILES * SSPLIT);
  int rem = bid - b * (RTILES * SSPLIT);
  int rt  = rem / SSPLIT;
  int ss  = rem - rt * SSPLIT;
  int tid  = threadIdx.x;
  int w    = tid >> 6;     // feature slice 0..3
  int lane = tid & 63;     // local receiver
  int r    = rt * 64 + lane;

  const float* src = nf + (size_t)(b * NN + ss * CHUNK) * NF;
  for (int i = tid; i < CHUNK * NF; i += 256) ((float*)snf)[i] = src[i];

  const float* xp = x + ((size_t)b * NN + r) * 3;
  float xr0 = xp[0], xr1 = xp[1], xr2 = xp[2];
  __syncthreads();

  float a0[16];
  float a1[8][3];
#pragma unroll
  for (int k = 0; k < 16; k++) a0[k] = 0.0f;
#pragma unroll
  for (int c = 0; c < 8; c++) { a1[c][0] = 0.0f; a1[c][1] = 0.0f; a1[c][2] = 0.0f; }

  const uint32_t* tbase = (const uint32_t*)table_l;

  auto geom_gather = [&](int i, float& u0, float& u1, float& u2, uint4* qq) {
    const float* sn = &snf[i][0];
    float xs0 = sn[384], xs1 = sn[385], xs2 = sn[386];   // LDS broadcast
    float v0 = xr0 - xs0, v1 = xr1 - xs1, v2 = xr2 - xs2;
    float d = sqrtf(v0 * v0 + v1 * v1 + v2 * v2);
    float inv = 1.0f / (d + 1e-8f);
    u0 = v0 * inv; u1 = v1 * inv; u2 = v2 * inv;
    int j = (int)fminf(d * TSCALE + 0.5f, (float)(TROWS - 1));
    if (ss * CHUNK + i == r) j = TROWS;                  // diagonal -> zero row
    const uint4* tp = (const uint4*)(tbase + (size_t)j * (RWN / 2) + w * 24);
#pragma unroll
    for (int m = 0; m < 6; m++) qq[m] = tp[m];           // 96B gather
  };

  float cu0, cu1, cu2;
  uint4 q[6];
  geom_gather(0, cu0, cu1, cu2, q);

  for (int i = 0; i < CHUNK; i++) {
    float nu0, nu1, nu2;
    uint4 qn[6];
    if (i + 1 < CHUNK) geom_gather(i + 1, nu0, nu1, nu2, qn);  // prefetch next

    uint32_t dwv[24];
#pragma unroll
    for (int m = 0; m < 6; m++) ((uint4*)dwv)[m] = q[m];
    float wv[48];   // [w0(16)|w3(16)|w1(8)|w2(8)] for this slice
#pragma unroll
    for (int m = 0; m < 24; m++) {
      wv[2 * m]     = __uint_as_float(dwv[m] << 16);
      wv[2 * m + 1] = __uint_as_float(dwv[m] & 0xffff0000u);
    }
    const float* sn = &snf[i][0];
#pragma unroll
    for (int k = 0; k < 16; k++) {        // a0 slice: w0*hm + w3*(u . hv0)
      float hmv = sn[w * 16 + k];
      float h0 = sn[192 +       w * 16 + k];
      float h1 = sn[192 +  64 + w * 16 + k];
      float h2 = sn[192 + 128 + w * 16 + k];
      float dv = cu0 * h0 + cu1 * h1 + cu2 * h2;
      a0[k] += wv[k] * hmv + wv[16 + k] * dv;
    }
#pragma unroll
    for (int c = 0; c < 8; c++) {         // a1 slice: (w1*hsv + w2*(u.hvv))*u - (w2/3)*hvv
      int ch = w * 8 + c;
      float hsvv = sn[64 + ch];
      float g0 = sn[96 + ch * 3 + 0];
      float g1 = sn[96 + ch * 3 + 1];
      float g2 = sn[96 + ch * 3 + 2];
      float qd = cu0 * g0 + cu1 * g1 + cu2 * g2;
      float coef = wv[32 + c] * hsvv + wv[40 + c] * qd;
      float t3 = wv[40 + c] * (1.0f / 3.0f);
      a1[c][0] += coef * cu0 - t3 * g0;
      a1[c][1] += coef * cu1 - t3 * g1;
      a1[c][2] += coef * cu2 - t3 * g2;
    }
    if (i + 1 < CHUNK) {
      cu0 = nu0; cu1 = nu1; cu2 = nu2;
#pragma unroll
      for (int m = 0; m < 6; m++) q[m] = qn[m];
    }
  }

  float* pw = partial + (size_t)(b * SSPLIT + ss) * ACC * NN;
#pragma unroll
  for (int k = 0; k < 16; k++) pw[(w * 16 + k) * NN + r] = a0[k];
#pragma unroll
  for (int c = 0; c < 8; c++) {
    int ch = w * 8 + c;
#pragma unroll
    for (int i = 0; i < 3; i++) pw[(64 + ch * 3 + i) * NN + r] = a1[c][i];
  }
}

// ---------------------------------------------------------------------------
// Reduce partials, polynomial correction, node update (weights pre-offset).
// ---------------------------------------------------------------------------
__global__ void update_k(const float* __restrict__ partial, const float* __restrict__ Wc,
                         const float* __restrict__ Wself,
                         float* __restrict__ h_s, float* __restrict__ h_v) {
  int node = blockIdx.x;
  int b = node >> 9, n = node & 511;
  int lane = threadIdx.x;   // 64
  __shared__ float a0s[F0], a2s[F0], a3s[F0], hss[F0];
  const float invn = 1.0f / (float)NN;
  float a = 0.0f;
  for (int ss = 0; ss < SSPLIT; ss++)
    a += partial[((size_t)(b * SSPLIT + ss) * ACC + lane) * NN + n];
  a *= invn;
  a0s[lane] = a; a2s[lane] = a * a; a3s[lane] = a * a * a;
  hss[lane] = h_s[(size_t)node * F0 + lane];
  for (int o = lane; o < 96; o += 64) {
    float v = 0.0f;
    for (int ss = 0; ss < SSPLIT; ss++)
      v += partial[((size_t)(b * SSPLIT + ss) * ACC + 64 + o) * NN + n];
    h_v[(size_t)node * F1 * 3 + o] += v * invn;
  }
  __syncthreads();
  float val = 0.0f;
  for (int f = 0; f < F0; f++) {
    val += hss[f] * Wself[f * F0 + lane];
    val += a0s[f] * Wc[(0 * F0 + f) * F0 + lane];
    val += a2s[f] * Wc[(1 * F0 + f) * F0 + lane];
    val += a3s[f] * Wc[(2 * F0 + f) * F0 + lane];
  }
  h_s[(size_t)node * F0 + lane] = val;
}

// Output head: vecf = h_v @ Woutv (first), inv = silu(h_s)@Wouts@Wfin + bfin.
__global__ void out_k(const float* __restrict__ h_s, const float* __restrict__ h_v,
                      const float* __restrict__ Wouts, const float* __restrict__ Wfin,
                      const float* __restrict__ bfin, const float* __restrict__ Woutv,
                      float* __restrict__ out) {
  int node = blockIdx.x;
  int lane = threadIdx.x;   // 64
  __shared__ float t[F0], g[NINVD];
  float h = h_s[(size_t)node * F0 + lane];
  t[lane] = h / (1.0f + __expf(-h));
  __syncthreads();
  float a = 0.0f;
  for (int f = 0; f < F0; f++) a += t[f] * Wouts[f * NINVD + lane];
  g[lane] = a;
  __syncthreads();
  float v = bfin[lane];
  for (int k = 0; k < NINVD; k++) v += g[k] * Wfin[k * NINVD + lane];
  out[INV_OFF + (size_t)node * NINVD + lane] = v;
  if (lane < NVECD * 3) {
    int gg = lane / 3, i = lane - gg * 3;
    float s = 0.0f;
    for (int f = 0; f < F1; f++) s += h_v[(size_t)node * F1 * 3 + f * 3 + i] * Woutv[f * NVECD + gg];
    out[(size_t)node * (NVECD * 3) + lane] = s;
  }
}

extern "C" void kernel_launch(void* const* d_in, const int* in_sizes, int n_in,
                              void* d_out, int out_size, void* d_ws, size_t ws_size,
                              hipStream_t stream) {
  const float* x     = (const float*)d_in[0];
  // d_in[1] senders, d_in[2] receivers: dense-graph structure is known, unused.
  const float* embed = (const float*)d_in[3];
  const float* Wr1   = (const float*)d_in[4];
  const float* Wr2   = (const float*)d_in[5];
  const float* Wm    = (const float*)d_in[6];
  const float* Wc    = (const float*)d_in[7];
  const float* Wself = (const float*)d_in[8];
  const float* Wsv   = (const float*)d_in[9];
  const float* Wvv   = (const float*)d_in[10];
  const float* Wv0   = (const float*)d_in[11];
  const float* Wouts = (const float*)d_in[12];
  const float* Woutv = (const float*)d_in[13];
  const float* Wfin  = (const float*)d_in[14];
  const float* bfin  = (const float*)d_in[15];
  float* out = (float*)d_out;

  char* ws = (char*)d_ws;
  size_t off = 0;
  auto wsalloc = [&](size_t bytes) {
    void* p = ws + off;
    off += (bytes + 255) & ~(size_t)255;
    return p;
  };
  __hip_bfloat16* table = (__hip_bfloat16*)wsalloc((size_t)LNUM * (TROWS + 1) * RWN * 2);
  float* h_s     = (float*)wsalloc((size_t)BB * NN * F0 * 4);
  float* h_v     = (float*)wsalloc((size_t)BB * NN * F1 * 3 * 4);
  float* nf      = (float*)wsalloc((size_t)BB * NN * NF * 4);
  float* partial = (float*)wsalloc((size_t)BB * SSPLIT * ACC * NN * 4);
  // total workspace: ~28.6 MB

  table_k<<<LNUM * (TROWS + 1), 64, 0, stream>>>(Wr1, Wr2, table);
  init_k<<<(BB * NN * F1 * 3 + 255) / 256, 256, 0, stream>>>(embed, h_s, h_v);
  for (int l = 0; l < LNUM; l++) {
    nodeprep_k<<<BB * NN, 64, 0, stream>>>(h_s, h_v, x,
                                           Wm + l * F0 * F0, Wsv + l * F0 * F1,
                                           Wvv + l * F1 * F1, Wv0 + l * F1 * F0, nf);
    msg_k<<<BB * RTILES * SSPLIT, 256, 0, stream>>>(nf, table + (size_t)l * (TROWS + 1) * RWN,
                                                    x, partial);
    update_k<<<BB * NN, 64, 0, stream>>>(partial, Wc + l * 3 * F0 * F0,
                                         Wself + l * F0 * F0, h_s, h_v);
  }
  out_k<<<BB * NN, 64, 0, stream>>>(h_s, h_v, Wouts, Wfin, bfin, Woutv, out);
}